// Round 1
// baseline (65.926 us; speedup 1.0000x reference)
//
#include <hip/hip_runtime.h>

// Problem constants (from reference)
constexpr int NUM_BIN  = 64;
constexpr int NUM_CAT  = 1024;   // 64 groups x 16
constexpr int NUM_NUM  = 4096;   // 256 groups x 16
constexpr int IN1_C    = NUM_BIN + NUM_CAT + NUM_NUM;   // 5184
constexpr int IN2_C    = 64 + 64 + 256;                 // 384
constexpr int BATCH_C  = 16384;
constexpr int NF4      = IN1_C / 4;                     // 1296 float4 per row

// ---------------------------------------------------------------------------
// Kernel 1: compute eff_w[c] = w1[c] * w2[j(c)]  and
//           cst = sum_c b1[c]*w2[j(c)] + sum_j b2[j]
// Single block, 1024 threads. Fully overwrites its workspace region each call.
// ---------------------------------------------------------------------------
__global__ __launch_bounds__(1024) void pwl_prep(
    const float* __restrict__ w1, const float* __restrict__ b1,
    const float* __restrict__ w2, const float* __restrict__ b2,
    float* __restrict__ effw, float* __restrict__ cst)
{
    const int t = threadIdx.x;
    float local = 0.f;
    for (int c = t; c < IN1_C; c += 1024) {
        int j;
        if (c < NUM_BIN)                j = c;
        else if (c < NUM_BIN + NUM_CAT) j = NUM_BIN + ((c - NUM_BIN) >> 4);
        else                            j = 128 + ((c - NUM_BIN - NUM_CAT) >> 4);
        const float w2j = w2[j];
        effw[c] = w1[c] * w2j;
        local  += b1[c] * w2j;
    }
    if (t < IN2_C) local += b2[t];

    // block reduction: wave shuffle then LDS
    for (int off = 32; off > 0; off >>= 1)
        local += __shfl_down(local, off, 64);
    __shared__ float red[16];
    const int lane = t & 63, wid = t >> 6;
    if (lane == 0) red[wid] = local;
    __syncthreads();
    if (t == 0) {
        float s = 0.f;
        #pragma unroll
        for (int i = 0; i < 16; ++i) s += red[i];
        *cst = s;
    }
}

// ---------------------------------------------------------------------------
// Kernel 2: one wave per row. out[r] = dot(x[r,:], effw) + cst
// 256 threads/block = 4 waves = 4 rows per block. float4 coalesced loads.
// ---------------------------------------------------------------------------
__global__ __launch_bounds__(256) void pwl_main(
    const float* __restrict__ x, const float* __restrict__ effw,
    const float* __restrict__ cst, float* __restrict__ out)
{
    const int gwave = (int)((blockIdx.x * blockDim.x + threadIdx.x) >> 6); // row
    const int lane  = threadIdx.x & 63;
    if (gwave >= BATCH_C) return;

    const float4* __restrict__ xr = (const float4*)(x + (size_t)gwave * IN1_C);
    const float4* __restrict__ w4 = (const float4*)effw;

    float sum = 0.f;
    #pragma unroll
    for (int k = 0; k < 20; ++k) {
        const float4 a = xr[lane + 64 * k];
        const float4 w = w4[lane + 64 * k];
        sum += a.x * w.x + a.y * w.y + a.z * w.z + a.w * w.w;
    }
    // remainder: 1296 - 1280 = 16 float4
    if (lane < 16) {
        const float4 a = xr[lane + 1280];
        const float4 w = w4[lane + 1280];
        sum += a.x * w.x + a.y * w.y + a.z * w.z + a.w * w.w;
    }

    // wave-64 reduction
    for (int off = 32; off > 0; off >>= 1)
        sum += __shfl_down(sum, off, 64);

    if (lane == 0) out[gwave] = sum + *cst;
}

// ---------------------------------------------------------------------------
extern "C" void kernel_launch(void* const* d_in, const int* in_sizes, int n_in,
                              void* d_out, int out_size, void* d_ws, size_t ws_size,
                              hipStream_t stream)
{
    const float* x  = (const float*)d_in[0];   // (16384, 5184, 1) f32
    const float* w1 = (const float*)d_in[1];   // (5184,)
    const float* b1 = (const float*)d_in[2];   // (5184,)
    const float* w2 = (const float*)d_in[3];   // (384,)
    const float* b2 = (const float*)d_in[4];   // (384,)
    float* out = (float*)d_out;                // (16384,)

    float* effw = (float*)d_ws;                // 5184 floats
    float* cst  = effw + IN1_C;                // 1 float

    pwl_prep<<<1, 1024, 0, stream>>>(w1, b1, w2, b2, effw, cst);

    const int blocks = BATCH_C / 4;            // 4 rows (waves) per 256-thread block
    pwl_main<<<blocks, 256, 0, stream>>>(x, effw, cst, out);
}